// Round 18
// baseline (646.725 us; speedup 1.0000x reference)
//
#include <hip/hip_runtime.h>

#define B_TOT 262144
#define HID   256
#define NHEAD 8
#define BR    128      // rows per block: 4 waves x 32 rows
#define NTHR  256

typedef __bf16 bf16_t;
typedef __attribute__((ext_vector_type(8)))  __bf16 bf16x8;
typedef __attribute__((ext_vector_type(4)))  float  f32x4;
typedef __attribute__((ext_vector_type(16))) float  f32x16;

// d_ws: [0,512K) packed W, 32 phases x 16 KB; byte = ph*16384 + s*1024 + lane*16.
//  ph=3h+{0,1,2} = Wq/Wk/Wv head h, K-step s=0..15:
//    lane l: W[h*32 + (l&31)][s*16 + (l>>5)*8 + j] j=0..7   (32x32x16 A-frag)
//  ph=24+jt = Wo block jt (out-cols jt*32..+31), K-step s (sigma-ordered):
//    h'=s>>1, t=s&1, p=l>>5; base = 32h' + 16t + 4p
//    lane l: Wo[jt*32 + (l&31)][base + {0..3, 8..11}]
//  sigma(16s+8p+j) = 32h' + 16t + 4p + (j&3) + 8*(j>>2): aligns mix C-frag
//  (row = (r&3)+8*(r>>2)+4p) with Wo B-frag slots: frag(2h)=m[0..7], frag(2h+1)=m[8..15].
// [512K, 512K+128M): mid bf16, offset((s*2+p)*B_TOT + row)*8 + j  — lane-private.
#define WPK_BYTES (512 * 1024)

#define PHASE_SYNC(N)                                                  \
  do {                                                                 \
    asm volatile("s_waitcnt vmcnt(" #N ") lgkmcnt(0)" ::: "memory");   \
    __builtin_amdgcn_s_barrier();                                      \
  } while (0)

static __device__ __forceinline__ f32x16 mfma32(bf16x8 a, bf16x8 b, f32x16 c) {
  return __builtin_amdgcn_mfma_f32_32x32x16_bf16(a, b, c, 0, 0, 0);
}

static __device__ __forceinline__ bf16x8 cvt8(float4 a, float4 b) {
  bf16x8 r;
  r[0] = (bf16_t)a.x; r[1] = (bf16_t)a.y; r[2] = (bf16_t)a.z; r[3] = (bf16_t)a.w;
  r[4] = (bf16_t)b.x; r[5] = (bf16_t)b.y; r[6] = (bf16_t)b.z; r[7] = (bf16_t)b.w;
  return r;
}

static __device__ __forceinline__ bf16x8 pin8(bf16x8 v) {
  f32x4 t = __builtin_bit_cast(f32x4, v);
  asm volatile("" : "+v"(t));
  return __builtin_bit_cast(bf16x8, t);
}

typedef __attribute__((address_space(3))) void lds_void;
typedef __attribute__((address_space(1))) void gbl_void;
static __device__ __forceinline__ void gload_lds16(const void* g, void* l) {
  __builtin_amdgcn_global_load_lds((gbl_void*)g, (lds_void*)l, 16, 0, 0);
}

// ---- one-shot weight pack (32x32 fragment order) ----
__global__ __launch_bounds__(256) void pack_weights(
    const float* __restrict__ Wq, const float* __restrict__ Wk,
    const float* __restrict__ Wv, const float* __restrict__ Wo,
    bf16_t* __restrict__ ws) {
  const int t     = blockIdx.x * 256 + threadIdx.x;   // 0..32767
  const int lane  = t & 63;
  const int chunk = t >> 6;                           // 0..511
  const int ph = chunk >> 4, s = chunk & 15;
  const int l31 = lane & 31, p = lane >> 5;
  float4 a, b;
  if (ph < 24) {
    const int h = ph / 3, w = ph % 3;
    const float* src = (w == 0) ? Wq : (w == 1) ? Wk : Wv;
    const float* q = src + (size_t)(h * 32 + l31) * HID + s * 16 + p * 8;
    a = *(const float4*)q;
    b = *(const float4*)(q + 4);
  } else {
    const int jt = ph - 24;
    const int hh = s >> 1, tt = s & 1;
    const int base = 32 * hh + 16 * tt + 4 * p;
    const float* q = Wo + (size_t)(jt * 32 + l31) * HID + base;
    a = *(const float4*)q;
    b = *(const float4*)(q + 8);
  }
  *(bf16x8*)(ws + (size_t)t * 8) = cvt8(a, b);
}

__global__ __launch_bounds__(NTHR, 2) void fused_local_aug(
    const float* __restrict__ fine, const float* __restrict__ coarse,
    const float* __restrict__ motif, const bf16_t* __restrict__ wpk,
    bf16_t* __restrict__ mid, const float* __restrict__ bo,
    float* __restrict__ out) {
  __shared__ char wbuf[49152];   // 3 x 16 KB

  const int tid  = threadIdx.x;
  const int lane = tid & 63;
  const int wave = tid >> 6;
  const int l31  = lane & 31;
  const int p    = lane >> 5;
  const size_t row = (size_t)blockIdx.x * BR + wave * 32 + l31;  // lane's batch row

  auto stage = [&](int ph) {
    char* dst = wbuf + (ph % 3) * 16384 + tid * 16;
    const char* src = (const char*)wpk + (size_t)ph * 16384 + tid * 16;
#pragma unroll
    for (int i = 0; i < 4; ++i)
      gload_lds16(src + i * 4096, dst + i * 4096);
  };

  stage(0);
  stage(1);

  // ---- X in registers: 16 K-step frags x 3 inputs (192 VGPRs) ----
  bf16x8 xm[16], xf[16], xc[16];
  {
    const float* pm = motif  + row * HID + p * 8;
    const float* pf = fine   + row * HID + p * 8;
    const float* pc = coarse + row * HID + p * 8;
#pragma unroll
    for (int s = 0; s < 16; ++s) {
      xm[s] = pin8(cvt8(*(const float4*)(pm + s * 16), *(const float4*)(pm + s * 16 + 4)));
      xf[s] = pin8(cvt8(*(const float4*)(pf + s * 16), *(const float4*)(pf + s * 16 + 4)));
      xc[s] = pin8(cvt8(*(const float4*)(pc + s * 16), *(const float4*)(pc + s * 16 + 4)));
    }
  }
  __syncthreads();   // phases 0,1 staged for all waves

  f32x16 aQ{}, aK1{}, aK2{}, aV1{}, aV2{};
  float ps1 = 0.f, ps2 = 0.f;
  bf16x8 mf14, mf15;                    // head-7 frags kept in-reg

  bf16_t* midp = mid + (size_t)(p)*B_TOT * 8 + row * 8;  // +(s*2)*B_TOT*8 per frag

  // finish head hh (uses ps, aV): softmax + mix -> mid (hh<7) or regs (hh=7)
  auto finish = [&](int hh) {
    float s1 = ps1 + __shfl_xor(ps1, 32);
    float s2 = ps2 + __shfl_xor(ps2, 32);
    s1 *= (1.0f / 32.0f);  s2 *= (1.0f / 32.0f);   // reference divides by d_k=32
    const float mx = fmaxf(s1, s2);
    const float e1 = __expf(s1 - mx), e2 = __expf(s2 - mx);
    const float a1 = e1 / (e1 + e2);
    const float a2 = 1.0f - a1;
    bf16x8 f0, f1;
#pragma unroll
    for (int j = 0; j < 8; ++j) {
      f0[j] = (bf16_t)(a1 * aV1[j]     + a2 * aV2[j]);
      f1[j] = (bf16_t)(a1 * aV1[j + 8] + a2 * aV2[j + 8]);
    }
    if (hh < NHEAD - 1) {
      *(bf16x8*)(midp + (size_t)(2 * hh) * 2 * B_TOT * 8)     = f0;
      *(bf16x8*)(midp + (size_t)(2 * hh + 1) * 2 * B_TOT * 8) = f1;
    } else { mf14 = f0; mf15 = f1; }
  };

#pragma unroll
  for (int h = 0; h < NHEAD; ++h) {
    {  // -- Q phase (ph = 3h): finish(h-1) overlaps Q MFMAs (scheduler-free) --
      const int ph = 3 * h;
      if (ph > 0) PHASE_SYNC(4);
      stage(ph + 2);
      if (h > 0) finish(h - 1);
      aQ = f32x16{};
      const char* pb = wbuf + (ph % 3) * 16384 + lane * 16;
      __builtin_amdgcn_s_setprio(1);
#pragma unroll
      for (int s = 0; s < 16; ++s)
        aQ = mfma32(*(const bf16x8*)(pb + s * 1024), xm[s], aQ);
      __builtin_amdgcn_s_setprio(0);
    }
    {  // -- K phase (ph = 3h+1): shared k-frag feeds both fine & coarse --
      const int ph = 3 * h + 1;
      PHASE_SYNC(4);
      stage(ph + 2);
      aK1 = f32x16{}; aK2 = f32x16{};
      const char* pb = wbuf + (ph % 3) * 16384 + lane * 16;
      __builtin_amdgcn_s_setprio(1);
#pragma unroll
      for (int s = 0; s < 16; ++s) {
        bf16x8 k = *(const bf16x8*)(pb + s * 1024);
        aK1 = mfma32(k, xf[s], aK1);
        aK2 = mfma32(k, xc[s], aK2);
      }
      __builtin_amdgcn_s_setprio(0);
      float s1 = 0.f, s2 = 0.f;
#pragma unroll
      for (int r = 0; r < 16; ++r) {
        s1 += aQ[r] * aK1[r];
        s2 += aQ[r] * aK2[r];
      }
      ps1 = s1; ps2 = s2;            // aQ, aK dead after this
    }
    {  // -- V phase (ph = 3h+2) --
      const int ph = 3 * h + 2;
      PHASE_SYNC(4);
      stage(ph + 2);
      aV1 = f32x16{}; aV2 = f32x16{};
      const char* pb = wbuf + (ph % 3) * 16384 + lane * 16;
      __builtin_amdgcn_s_setprio(1);
#pragma unroll
      for (int s = 0; s < 16; ++s) {
        bf16x8 v = *(const bf16x8*)(pb + s * 1024);
        aV1 = mfma32(v, xf[s], aV1);
        aV2 = mfma32(v, xc[s], aV2);
      }
      __builtin_amdgcn_s_setprio(0);
    }
  }
  finish(NHEAD - 1);                 // -> mf14, mf15 in regs

  // drain: all mid stores (and stage(25)) complete before reload
  asm volatile("s_waitcnt vmcnt(0)" ::: "memory");

  bf16x8 mf[16];
#pragma unroll
  for (int s = 0; s < 14; ++s)
    mf[s] = *(const bf16x8*)(midp + (size_t)s * 2 * B_TOT * 8);
  mf[14] = mf14;
  mf[15] = mf15;

  // ---- output projection: 8 Wo phases (ph = 24+jt), one 32-col block each ----
#pragma unroll
  for (int jt = 0; jt < 8; ++jt) {
    const int ph = 24 + jt;
    PHASE_SYNC(4);
    if (jt < 6) stage(ph + 2);
    f32x16 acc{};
    const char* pb = wbuf + (ph % 3) * 16384 + lane * 16;
    __builtin_amdgcn_s_setprio(1);
#pragma unroll
    for (int s = 0; s < 16; ++s)
      acc = mfma32(*(const bf16x8*)(pb + s * 1024), mf[s], acc);
    __builtin_amdgcn_s_setprio(0);
    // epilogue: C row = (r&3)+8*(r>>2)+4p -> cols jt*32 + 8b + 4p + (0..3)
#pragma unroll
    for (int b = 0; b < 4; ++b) {
      const int col = jt * 32 + 8 * b + 4 * p;
      const float4 b4 = *(const float4*)(bo + col);
      f32x4 o;
      o[0] = acc[4 * b + 0] + b4.x;
      o[1] = acc[4 * b + 1] + b4.y;
      o[2] = acc[4 * b + 2] + b4.z;
      o[3] = acc[4 * b + 3] + b4.w;
      __builtin_nontemporal_store(o, (f32x4*)(out + row * HID + col));
    }
  }
}

extern "C" void kernel_launch(void* const* d_in, const int* in_sizes, int n_in,
                              void* d_out, int out_size, void* d_ws, size_t ws_size,
                              hipStream_t stream) {
  (void)in_sizes; (void)n_in; (void)ws_size; (void)out_size;
  const float* fine   = (const float*)d_in[0];
  const float* coarse = (const float*)d_in[1];
  const float* motif  = (const float*)d_in[2];
  const float* Wq     = (const float*)d_in[3];
  const float* Wk     = (const float*)d_in[4];
  const float* Wv     = (const float*)d_in[5];
  const float* Wo     = (const float*)d_in[6];
  const float* bo     = (const float*)d_in[7];
  float* out          = (float*)d_out;
  bf16_t* wpk         = (bf16_t*)d_ws;
  bf16_t* mid         = (bf16_t*)((char*)d_ws + WPK_BYTES);  // ws_size OK (R12/R16 ran)

  pack_weights<<<128, 256, 0, stream>>>(Wq, Wk, Wv, Wo, wpk);
  fused_local_aug<<<B_TOT / BR, NTHR, 0, stream>>>(fine, coarse, motif, wpk,
                                                   mid, bo, out);
}

// Round 19
// 348.504 us; speedup vs baseline: 1.8557x; 1.8557x over previous
//
#include <hip/hip_runtime.h>

#define B_TOT 262144
#define HID   256
#define NHEAD 8
#define BR    64       // rows per block
#define NTHR  256      // 4 waves; wave owns 16 batch rows end-to-end

typedef __bf16 bf16_t;
typedef __attribute__((ext_vector_type(8))) __bf16 bf16x8;
typedef __attribute__((ext_vector_type(4))) float  f32x4;

// d_ws layout (bf16): 32 sequential PHASES of 16 KB. byte = ph*16384 + c*1024 + lane*16
//   ph = 3h+0 (Q) / 3h+1 (K) / 3h+2 (V), h in 0..7 : c = ks*2 + half
//        element = W[h*32 + PI(lane&15,half)][ks*32 + (lane>>4)*8 .. +8]
//        PI(m,half) = (m>>2)*8 + half*4 + (m&3)
//        (PI => attention-mix C-frag holds CONTIGUOUS true features -> out-proj B-frag)
//   ph = 24+ks (Wo) : c = jt; element = Wo[jt*16+(lane&15)][ks*32+(lane>>4)*8 ..+8]
// Every phase = 16 KB = 4 gload_lds16/thread -> uniform counted vmcnt(4).

// Counted wait + barrier. lgkmcnt(0): all ds_reads of the retiring buffer are
// complete before anyone passes the barrier (stage(p+2) then can't clobber them).
// NO sched_barrier: "memory" clobber already orders memory ops; register-only
// MFMAs may sink across the barrier, which is harmless and lets the scheduler
// overlap softmax / stage issue with MFMA clusters.
#define PHASE_SYNC(N)                                                  \
  do {                                                                 \
    asm volatile("s_waitcnt vmcnt(" #N ") lgkmcnt(0)" ::: "memory");   \
    __builtin_amdgcn_s_barrier();                                      \
  } while (0)

static __device__ __forceinline__ f32x4 mfma16(bf16x8 a, bf16x8 b, f32x4 c) {
  return __builtin_amdgcn_mfma_f32_16x16x32_bf16(a, b, c, 0, 0, 0);
}

static __device__ __forceinline__ bf16x8 cvt8(float4 a, float4 b) {
  bf16x8 r;
  r[0] = (bf16_t)a.x; r[1] = (bf16_t)a.y; r[2] = (bf16_t)a.z; r[3] = (bf16_t)a.w;
  r[4] = (bf16_t)b.x; r[5] = (bf16_t)b.y; r[6] = (bf16_t)b.z; r[7] = (bf16_t)b.w;
  return r;
}

// opaque register pin: forbids rematerialization of the producing loads
static __device__ __forceinline__ bf16x8 pin8(bf16x8 v) {
  f32x4 t = __builtin_bit_cast(f32x4, v);
  asm volatile("" : "+v"(t));
  return __builtin_bit_cast(bf16x8, t);
}

typedef __attribute__((address_space(3))) void lds_void;
typedef __attribute__((address_space(1))) void gbl_void;
static __device__ __forceinline__ void gload_lds16(const void* g, void* l) {
  __builtin_amdgcn_global_load_lds((gbl_void*)g, (lds_void*)l, 16, 0, 0);
}

// ---- one-shot weight pack (flat 32-phase layout) ----
__global__ __launch_bounds__(256) void pack_weights(
    const float* __restrict__ Wq, const float* __restrict__ Wk,
    const float* __restrict__ Wv, const float* __restrict__ Wo,
    bf16_t* __restrict__ ws) {
  const int t     = blockIdx.x * 256 + threadIdx.x;
  const int lane  = t & 63;
  const int chunk = t >> 6;
  const int l15 = lane & 15, lg = lane >> 4;
  const float* src;
  int row, col;
  if (chunk < 384) {
    const int ph = chunk >> 4;
    const int c  = chunk & 15;
    const int h = ph / 3, w = ph % 3;
    const int ks = c >> 1, half = c & 1;
    src = (w == 0) ? Wq : (w == 1) ? Wk : Wv;
    row = h * 32 + (l15 >> 2) * 8 + half * 4 + (l15 & 3);   // PI permutation
    col = ks * 32 + lg * 8;
  } else {
    const int c  = chunk - 384;
    const int ks = c >> 4, jt = c & 15;
    src = Wo;
    row = jt * 16 + l15;
    col = ks * 32 + lg * 8;
  }
  const float* p = src + (size_t)row * HID + col;
  *(bf16x8*)(ws + (size_t)t * 8) = cvt8(*(const float4*)p, *(const float4*)(p + 4));
}

__global__ __launch_bounds__(NTHR, 2) void fused_local_aug(
    const float* __restrict__ fine, const float* __restrict__ coarse,
    const float* __restrict__ motif, const bf16_t* __restrict__ wpk,
    const float* __restrict__ bo, float* __restrict__ out) {
  __shared__ char wbuf[49152];   // 3 x 16 KB

  const int tid  = threadIdx.x;
  const int lane = tid & 63;
  const int wave = tid >> 6;
  const int l15  = lane & 15;
  const int lg   = lane >> 4;
  const size_t mrow = (size_t)blockIdx.x * BR + wave * 16 + l15;

  auto stage = [&](int ph) {
    char* dst = wbuf + (ph % 3) * 16384 + tid * 16;
    const char* src = (const char*)wpk + (size_t)ph * 16384 + tid * 16;
#pragma unroll
    for (int i = 0; i < 4; ++i)
      gload_lds16(src + i * 4096, dst + i * 4096);
  };

  stage(0);
  stage(1);

  bf16x8 xm[8], xf[8], xc[8];
  {
    const float* pm = motif  + mrow * HID + lg * 8;
    const float* pf = fine   + mrow * HID + lg * 8;
    const float* pc = coarse + mrow * HID + lg * 8;
#pragma unroll
    for (int s = 0; s < 8; ++s) {
      xm[s] = pin8(cvt8(*(const float4*)(pm + s * 32), *(const float4*)(pm + s * 32 + 4)));
      xf[s] = pin8(cvt8(*(const float4*)(pf + s * 32), *(const float4*)(pf + s * 32 + 4)));
      xc[s] = pin8(cvt8(*(const float4*)(pc + s * 32), *(const float4*)(pc + s * 32 + 4)));
    }
  }
  __syncthreads();   // full drain once: phases 0,1 staged for all waves

  bf16x8 mfrag[NHEAD];
  const f32x4 z4 = {0.f, 0.f, 0.f, 0.f};

  // double accumulator sets: softmax of head h-1 runs inside head h's Q phase
  f32x4 aQ0[2], aQ1[2], aK10[2], aK11[2], aK20[2], aK21[2],
        aV10[2], aV11[2], aV20[2], aV21[2];

#pragma unroll
  for (int h = 0; h < NHEAD; ++h) {
    const int cur = h & 1, prv = cur ^ 1;   // compile-time after unroll
    {  // -- phase Q (p = 3h): MFMA cluster, then DEFERRED softmax of head h-1 --
      const int p = 3 * h;
      if (p > 0) PHASE_SYNC(4);
      stage(p + 2);
      aQ0[cur] = z4; aQ1[cur] = z4;
      const char* pb = wbuf + (p % 3) * 16384 + lane * 16;
      __builtin_amdgcn_s_setprio(1);
#pragma unroll
      for (int ks = 0; ks < 8; ++ks) {
        bf16x8 q0 = *(const bf16x8*)(pb + ks * 2048);
        bf16x8 q1 = *(const bf16x8*)(pb + ks * 2048 + 1024);
        aQ0[cur] = mfma16(q0, xm[ks], aQ0[cur]);
        aQ1[cur] = mfma16(q1, xm[ks], aQ1[cur]);
      }
      __builtin_amdgcn_s_setprio(0);
      if (h > 0) {   // softmax + mix for head h-1 (overlaps this phase's MFMAs)
        float s1 = 0.f, s2 = 0.f;
#pragma unroll
        for (int r = 0; r < 4; ++r) {
          s1 += aQ0[prv][r] * aK10[prv][r] + aQ1[prv][r] * aK11[prv][r];
          s2 += aQ0[prv][r] * aK20[prv][r] + aQ1[prv][r] * aK21[prv][r];
        }
        s1 += __shfl_xor(s1, 16); s1 += __shfl_xor(s1, 32);
        s2 += __shfl_xor(s2, 16); s2 += __shfl_xor(s2, 32);
        s1 *= (1.0f / 32.0f);  s2 *= (1.0f / 32.0f);   // reference divides by d_k
        const float mx = fmaxf(s1, s2);
        const float e1 = __expf(s1 - mx), e2 = __expf(s2 - mx);
        const float a1 = e1 / (e1 + e2);
        const float a2 = 1.0f - a1;
        bf16x8 t;
#pragma unroll
        for (int r = 0; r < 4; ++r) {
          t[r]     = (bf16_t)(a1 * aV10[prv][r] + a2 * aV20[prv][r]);
          t[r + 4] = (bf16_t)(a1 * aV11[prv][r] + a2 * aV21[prv][r]);
        }
        mfrag[h - 1] = t;
      }
    }
    {  // -- phase K (p = 3h+1) --
      const int p = 3 * h + 1;
      PHASE_SYNC(4);
      stage(p + 2);
      aK10[cur] = z4; aK11[cur] = z4; aK20[cur] = z4; aK21[cur] = z4;
      const char* pb = wbuf + (p % 3) * 16384 + lane * 16;
      __builtin_amdgcn_s_setprio(1);
#pragma unroll
      for (int ks = 0; ks < 8; ++ks) {
        bf16x8 k0 = *(const bf16x8*)(pb + ks * 2048);
        bf16x8 k1 = *(const bf16x8*)(pb + ks * 2048 + 1024);
        aK10[cur] = mfma16(k0, xf[ks], aK10[cur]);
        aK11[cur] = mfma16(k1, xf[ks], aK11[cur]);
        aK20[cur] = mfma16(k0, xc[ks], aK20[cur]);
        aK21[cur] = mfma16(k1, xc[ks], aK21[cur]);
      }
      __builtin_amdgcn_s_setprio(0);
    }
    {  // -- phase V (p = 3h+2) --
      const int p = 3 * h + 2;
      PHASE_SYNC(4);
      stage(p + 2);
      aV10[cur] = z4; aV11[cur] = z4; aV20[cur] = z4; aV21[cur] = z4;
      const char* pb = wbuf + (p % 3) * 16384 + lane * 16;
      __builtin_amdgcn_s_setprio(1);
#pragma unroll
      for (int ks = 0; ks < 8; ++ks) {
        bf16x8 v0 = *(const bf16x8*)(pb + ks * 2048);
        bf16x8 v1 = *(const bf16x8*)(pb + ks * 2048 + 1024);
        aV10[cur] = mfma16(v0, xf[ks], aV10[cur]);
        aV11[cur] = mfma16(v1, xf[ks], aV11[cur]);
        aV20[cur] = mfma16(v0, xc[ks], aV20[cur]);
        aV21[cur] = mfma16(v1, xc[ks], aV21[cur]);
      }
      __builtin_amdgcn_s_setprio(0);
    }
  }
  {  // softmax + mix for the last head (h = 7, set index 1)
    const int prv = 1;
    float s1 = 0.f, s2 = 0.f;
#pragma unroll
    for (int r = 0; r < 4; ++r) {
      s1 += aQ0[prv][r] * aK10[prv][r] + aQ1[prv][r] * aK11[prv][r];
      s2 += aQ0[prv][r] * aK20[prv][r] + aQ1[prv][r] * aK21[prv][r];
    }
    s1 += __shfl_xor(s1, 16); s1 += __shfl_xor(s1, 32);
    s2 += __shfl_xor(s2, 16); s2 += __shfl_xor(s2, 32);
    s1 *= (1.0f / 32.0f);  s2 *= (1.0f / 32.0f);
    const float mx = fmaxf(s1, s2);
    const float e1 = __expf(s1 - mx), e2 = __expf(s2 - mx);
    const float a1 = e1 / (e1 + e2);
    const float a2 = 1.0f - a1;
    bf16x8 t;
#pragma unroll
    for (int r = 0; r < 4; ++r) {
      t[r]     = (bf16_t)(a1 * aV10[prv][r] + a2 * aV20[prv][r]);
      t[r + 4] = (bf16_t)(a1 * aV11[prv][r] + a2 * aV21[prv][r]);
    }
    mfrag[NHEAD - 1] = t;
  }

  // ---- output projection: 8 pipelined Wo phases (p = 24+wp) ----
  f32x4 acc[16];
#pragma unroll
  for (int jt = 0; jt < 16; ++jt) acc[jt] = z4;

#pragma unroll
  for (int wp = 0; wp < 8; ++wp) {
    const int p = 24 + wp;
    if (wp == 7) { PHASE_SYNC(0); } else { PHASE_SYNC(4); }
    if (wp < 6) stage(p + 2);
    bf16x8 m = mfrag[wp];
    const char* pb = wbuf + (p % 3) * 16384 + lane * 16;
    __builtin_amdgcn_s_setprio(1);
#pragma unroll
    for (int jt = 0; jt < 16; ++jt) {
      bf16x8 wf = *(const bf16x8*)(pb + jt * 1024);
      acc[jt] = mfma16(wf, m, acc[jt]);
    }
    __builtin_amdgcn_s_setprio(0);
  }

  // epilogue: bias + NT stores; lane writes 16B chunks of its own full row
#pragma unroll
  for (int jt = 0; jt < 16; ++jt) {
    const int jj = jt * 16 + lg * 4;
    const float4 b4 = *(const float4*)(bo + jj);
    f32x4 o;
    o[0] = acc[jt][0] + b4.x;
    o[1] = acc[jt][1] + b4.y;
    o[2] = acc[jt][2] + b4.z;
    o[3] = acc[jt][3] + b4.w;
    __builtin_nontemporal_store(o, (f32x4*)(out + mrow * HID + jj));
  }
}

extern "C" void kernel_launch(void* const* d_in, const int* in_sizes, int n_in,
                              void* d_out, int out_size, void* d_ws, size_t ws_size,
                              hipStream_t stream) {
  (void)in_sizes; (void)n_in; (void)ws_size; (void)out_size;
  const float* fine   = (const float*)d_in[0];
  const float* coarse = (const float*)d_in[1];
  const float* motif  = (const float*)d_in[2];
  const float* Wq     = (const float*)d_in[3];
  const float* Wk     = (const float*)d_in[4];
  const float* Wv     = (const float*)d_in[5];
  const float* Wo     = (const float*)d_in[6];
  const float* bo     = (const float*)d_in[7];
  float* out          = (float*)d_out;
  bf16_t* wpk         = (bf16_t*)d_ws;

  pack_weights<<<128, 256, 0, stream>>>(Wq, Wk, Wv, Wo, wpk);
  fused_local_aug<<<B_TOT / BR, NTHR, 0, stream>>>(fine, coarse, motif, wpk, bo, out);
}